// Round 8
// baseline (286.453 us; speedup 1.0000x reference)
//
#include <hip/hip_runtime.h>
#include <hip/hip_cooperative_groups.h>
#include <math.h>

namespace cg = cooperative_groups;

#define BB 4
#define NN 1024
#define DIN 128
#define DOUT 64
#define SLOPE 0.01f
#define CAP 256  // per-row edge capacity (nnz ~52±7)

// ws layout: [0, 1 MB) = x2 (B*N*64 fp32); [1 MB, 1 MB+32 KB) = lwP[64][128]
// lwP[k2*128 + d*2 + r] = lin_w[d*128 + 2*k2 + r]

__device__ __forceinline__ float fast_edge_exp(float sc) {
  // e = exp(8*tanh(sc/8)); tanh via exp, clamped so __expf stays finite
  float z = sc * 0.125f;
  z = fminf(10.f, fmaxf(-10.f, z));
  float u = __expf(2.f * z);
  float th = (u - 1.f) / (u + 1.f);
  return __expf(8.f * th);
}

// One cooperative kernel. Grid 2048 x 128 (2 waves/block, wave = one row,
// 16 waves/CU fully co-resident). Phase 1: per-wave projection (x1 -> LDS
// only; x2 -> 1 MB global). grid.sync(). Phase 2: per-wave fused
// compact+score+aggregate+epilogue (r7 structure, x2 stride 64).
__global__ __launch_bounds__(128, 4) void gat_fused_kernel(
    const float* __restrict__ x, const float* __restrict__ A_shape,
    const float* __restrict__ a_vec, const float* __restrict__ w1,
    const float* __restrict__ w2, const float* __restrict__ lin_w,
    float* __restrict__ x2g, float* __restrict__ lwP,
    float* __restrict__ out) {
  int tid = threadIdx.x;
  int w = tid >> 6;
  int lane = tid & 63;
  int bi = blockIdx.x * 2 + w;  // this wave's row
  int b = bi >> 10;

  __shared__ __align__(16) float xl[2][DIN];    // 1 KB: x row staging
  __shared__ __align__(16) float x1s[2][DOUT];  // 512 B: own-row x1
  __shared__ int eidx_s[2][CAP];                // 2 KB
  __shared__ __align__(16) float agg_s[2][DIN]; // 1 KB
  float* xlw = xl[w];
  float* x1w = x1s[w];
  int* eidx = eidx_s[w];
  float* aggw = agg_s[w];

  // ================= Phase 1: projection =================
  reinterpret_cast<float2*>(xlw)[lane] =
      reinterpret_cast<const float2*>(x + (size_t)bi * DIN)[lane];
  __syncthreads();
  {
    const float* w1c = w1 + lane;
    const float* w2c = w2 + lane;
    float a1 = 0.f, a2 = 0.f;
#pragma unroll 8
    for (int k = 0; k < DIN; ++k) {
      float xv = xlw[k];                   // LDS broadcast
      a1 = fmaf(xv, w1c[k * DOUT], a1);    // coalesced 256B, L1/L2-hot
      a2 = fmaf(xv, w2c[k * DOUT], a2);
    }
    x1w[lane] = a1;                        // x1 never leaves the CU
    x2g[(size_t)bi * DOUT + lane] = a2;    // 1 MB total
  }
  if (blockIdx.x < 64) {  // build lwP (8192 elems over 64 blocks)
    int idx = blockIdx.x * 128 + tid;
    int k2 = idx >> 7;
    int rem = idx & 127;
    int d = rem >> 1, r = rem & 1;
    lwP[idx] = lin_w[d * DIN + 2 * k2 + r];
  }

  cg::this_grid().sync();

  // ================= Phase 2: per-row GAT =================
  // ---- compact mask row (4x float4 coalesced loads) ----
  const float4* mrow4 =
      reinterpret_cast<const float4*>(A_shape + (size_t)bi * NN);
  float mvf[16];
#pragma unroll
  for (int c = 0; c < 4; ++c)
    *reinterpret_cast<float4*>(&mvf[c * 4]) = mrow4[c * 64 + lane];
  int base = 0;
#pragma unroll
  for (int c = 0; c < 4; ++c) {
#pragma unroll
    for (int q = 0; q < 4; ++q) {  // col = c*256 + lane*4 + q
      bool pred = (mvf[c * 4 + q] != 0.f);
      unsigned long long m = __ballot(pred);
      int prefix = __popcll(m & ((1ull << lane) - 1ull));
      int slot = base + prefix;
      if (pred && slot < CAP) eidx[slot] = c * 256 + lane * 4 + q;
      base += __popcll(m);  // wave-uniform
    }
  }
  int nz = base < CAP ? base : CAP;

  // ---- fused score+aggregate: 16-lane group g handles edge s+g ----
  int l16 = lane & 15;
  int grp = lane >> 4;
  float4 x1v = *reinterpret_cast<const float4*>(x1w + l16 * 4);  // LDS
  float4 avv = *reinterpret_cast<const float4*>(a_vec + l16 * 4);
  const float* x2b = x2g + (size_t)b * NN * DOUT;  // stride 64
  const float* xb = x + (size_t)b * NN * DIN;
  float acc[8] = {0.f, 0.f, 0.f, 0.f, 0.f, 0.f, 0.f, 0.f};
  float esum = 0.f;
  for (int s = 0; s < nz; s += 4) {
    int sg = s + grp;
    bool valid = sg < nz;
    int j = eidx[valid ? sg : nz - 1];  // LDS (4 distinct addrs/wave)
    // 3 coalesced gathers/group: 256B (x2 row) + 2x256B (x row)
    float4 x2v = *reinterpret_cast<const float4*>(x2b + (size_t)j * DOUT + l16 * 4);
    float4 xa = *reinterpret_cast<const float4*>(xb + (size_t)j * DIN + l16 * 8);
    float4 xc = *reinterpret_cast<const float4*>(xb + (size_t)j * DIN + l16 * 8 + 4);
    float z, sc = 0.f;
    z = x1v.x + x2v.x; sc = fmaf(z >= 0.f ? z : SLOPE * z, avv.x, sc);
    z = x1v.y + x2v.y; sc = fmaf(z >= 0.f ? z : SLOPE * z, avv.y, sc);
    z = x1v.z + x2v.z; sc = fmaf(z >= 0.f ? z : SLOPE * z, avv.z, sc);
    z = x1v.w + x2v.w; sc = fmaf(z >= 0.f ? z : SLOPE * z, avv.w, sc);
    sc += __shfl_xor(sc, 1, 64);
    sc += __shfl_xor(sc, 2, 64);
    sc += __shfl_xor(sc, 4, 64);
    sc += __shfl_xor(sc, 8, 64);  // all 16 lanes hold the group's score
    float e = valid ? fast_edge_exp(sc) : 0.f;
    esum += e;
    acc[0] = fmaf(e, xa.x, acc[0]);
    acc[1] = fmaf(e, xa.y, acc[1]);
    acc[2] = fmaf(e, xa.z, acc[2]);
    acc[3] = fmaf(e, xa.w, acc[3]);
    acc[4] = fmaf(e, xc.x, acc[4]);
    acc[5] = fmaf(e, xc.y, acc[5]);
    acc[6] = fmaf(e, xc.z, acc[6]);
    acc[7] = fmaf(e, xc.w, acc[7]);
  }
  // cross-group reduction
  esum += __shfl_xor(esum, 16, 64);
  esum += __shfl_xor(esum, 32, 64);
  float inv = 1.f / esum;
#pragma unroll
  for (int r = 0; r < 8; ++r) {
    acc[r] += __shfl_xor(acc[r], 16, 64);
    acc[r] += __shfl_xor(acc[r], 32, 64);
    acc[r] *= inv;
  }
  if (grp == 0) {  // lanes 0..15 hold agg[128]
    float4 lo = {acc[0], acc[1], acc[2], acc[3]};
    float4 hi = {acc[4], acc[5], acc[6], acc[7]};
    *reinterpret_cast<float4*>(aggw + l16 * 8) = lo;
    *reinterpret_cast<float4*>(aggw + l16 * 8 + 4) = hi;
  }
  __builtin_amdgcn_wave_barrier();  // per-wave LDS slice; lgkmcnt dep holds

  // ---- epilogue: out[d] = lrelu(sum_k agg[k]*lin_w[d,k]) via lwP ----
  float o = 0.f;
#pragma unroll 8
  for (int k2 = 0; k2 < 64; ++k2) {
    float2 ag = *reinterpret_cast<const float2*>(aggw + k2 * 2);  // broadcast
    float2 lw = *reinterpret_cast<const float2*>(lwP + k2 * 128 + lane * 2);
    o = fmaf(ag.y, lw.y, fmaf(ag.x, lw.x, o));
  }
  o = o >= 0.f ? o : SLOPE * o;
  out[(size_t)bi * DOUT + lane] = o;
}

extern "C" void kernel_launch(void* const* d_in, const int* in_sizes, int n_in,
                              void* d_out, int out_size, void* d_ws, size_t ws_size,
                              hipStream_t stream) {
  const float* x = (const float*)d_in[0];
  const float* A_shape = (const float*)d_in[1];
  const float* w1 = (const float*)d_in[2];
  const float* w2 = (const float*)d_in[3];
  const float* a = (const float*)d_in[4];
  const float* lin_w = (const float*)d_in[5];
  float* out = (float*)d_out;
  float* x2g = (float*)d_ws;                           // 1 MB
  float* lwP = (float*)d_ws + (size_t)BB * NN * DOUT;  // 32 KB

  void* args[] = {(void*)&x, (void*)&A_shape, (void*)&a,   (void*)&w1,
                  (void*)&w2, (void*)&lin_w,  (void*)&x2g, (void*)&lwP,
                  (void*)&out};
  hipLaunchCooperativeKernel((const void*)gat_fused_kernel,
                             dim3(BB * NN / 2), dim3(128), args, 0, stream);
}

// Round 9
// 101.073 us; speedup vs baseline: 2.8341x; 2.8341x over previous
//
#include <hip/hip_runtime.h>
#include <math.h>

#define BB 4
#define NN 1024
#define DIN 128
#define DOUT 64
#define SLOPE 0.01f

// ws layout: [0, 2 MB) = x12 (B*N*128 fp32); then lwT[128][64] (32 KB)

// Kernel 1: wave-per-row projection, grid 4096 rows + 8 transpose blocks.
// 16 waves/CU; k-loop unroll 8 keeps 16 independent L1-hot loads in flight.
__global__ __launch_bounds__(64, 8) void proj_kernel(
    const float* __restrict__ x, const float* __restrict__ w1,
    const float* __restrict__ w2, const float* __restrict__ lin_w,
    float* __restrict__ x12, float* __restrict__ lwT) {
  int l = threadIdx.x;
  if (blockIdx.x >= BB * NN) {
    // transpose lin_w [64][128] -> lwT [128][64]; 8 blocks x 1024 elems
    int base = (blockIdx.x - BB * NN) * 1024;
#pragma unroll
    for (int i = 0; i < 16; ++i) {
      int idx = base + i * 64 + l;        // flat over lin_w [d][k]
      int d = idx >> 7, k = idx & 127;
      lwT[k * DOUT + d] = lin_w[idx];     // coalesced read, scattered write
    }
    return;
  }
  int row = blockIdx.x;
  __shared__ __align__(16) float xl[DIN];
  reinterpret_cast<float2*>(xl)[l] =
      reinterpret_cast<const float2*>(x + (size_t)row * DIN)[l];
  __syncthreads();
  const float* w1c = w1 + l;
  const float* w2c = w2 + l;
  float a1 = 0.f, a2 = 0.f;
#pragma unroll 8
  for (int k = 0; k < DIN; ++k) {
    float xv = xl[k];                     // LDS broadcast
    a1 = fmaf(xv, w1c[k * DOUT], a1);     // coalesced 256B, L1-hot
    a2 = fmaf(xv, w2c[k * DOUT], a2);
  }
  x12[(size_t)row * 128 + l] = a1;
  x12[(size_t)row * 128 + DOUT + l] = a2;
}

__device__ __forceinline__ float fast_edge_exp(float sc) {
  // e = exp(8*tanh(sc/8)); tanh via exp, clamped so __expf stays finite
  float z = sc * 0.125f;
  z = fminf(10.f, fmaxf(-10.f, z));
  float u = __expf(2.f * z);
  float th = (u - 1.f) / (u + 1.f);
  return __expf(8.f * th);
}

// Kernel 2: TWO WAVES per (b,i) row (128 thr), grid 4096 -> 32 waves/CU.
// Wave w compacts mask columns [512w, 512w+512); edge list is two segments
// (seg0 at 0, seg1 at 512); phys(s) = s<nz0 ? s : 512+s-nz0.
__global__ __launch_bounds__(128, 8) void gat_row_kernel(
    const float* __restrict__ x, const float* __restrict__ A_shape,
    const float* __restrict__ a_vec, const float* __restrict__ lwT,
    const float* __restrict__ x12, float* __restrict__ out) {
  int bi = blockIdx.x;  // b*N + i
  int b = bi >> 10;
  int tid = threadIdx.x;
  int lane = tid & 63;
  int w = tid >> 6;

  __shared__ int eidx[1032];                  // seg0:[0,512) seg1:[512,1032)
  __shared__ float evals[1032];
  __shared__ __align__(16) float x1s[DOUT];
  __shared__ __align__(16) float avs[DOUT];
  __shared__ __align__(16) float agg[DIN];
  __shared__ float ep[2][DOUT];
  __shared__ float wsum[2];
  __shared__ int cnt[2];

  if (tid < DOUT) {
    x1s[tid] = x12[(size_t)bi * 128 + tid];
    avs[tid] = a_vec[tid];
  }

  // ---- Phase A: each wave compacts its 512 mask columns (2x float4) ----
  const float4* mrow4 = reinterpret_cast<const float4*>(
      A_shape + (size_t)bi * NN + w * 512);
  float mvf[8];
  *reinterpret_cast<float4*>(&mvf[0]) = mrow4[lane];
  *reinterpret_cast<float4*>(&mvf[4]) = mrow4[64 + lane];
  int base = 0;
  int seg = w * 512;
#pragma unroll
  for (int c = 0; c < 2; ++c) {
#pragma unroll
    for (int q = 0; q < 4; ++q) {  // col = w*512 + c*256 + lane*4 + q
      bool pred = (mvf[c * 4 + q] != 0.f);
      unsigned long long m = __ballot(pred);
      int prefix = __popcll(m & ((1ull << lane) - 1ull));
      if (pred) eidx[seg + base + prefix] = w * 512 + c * 256 + lane * 4 + q;
      base += __popcll(m);  // wave-uniform
    }
  }
  if (lane == 0) cnt[w] = base;
  __syncthreads();

  int nz0 = cnt[0], nz1 = cnt[1];
  int nzt = nz0 + nz1;
  int nzt8 = (nzt + 7) & ~7;
  if (tid < 8) {  // zero-weight pad edges after seg1 (capacity 512+8)
    eidx[512 + nz1 + tid] = bi & (NN - 1);
    evals[512 + nz1 + tid] = 0.f;
  }
  __syncthreads();

  // ---- Phase B: 8 groups x 16 lanes, 8 edges per iteration ----
  const float* x2b = x12 + (size_t)b * NN * 128 + DOUT;  // x2 half, stride 128
  int l16 = tid & 15;
  int grp = tid >> 4;
  float4 x1v = reinterpret_cast<const float4*>(x1s)[l16];
  float4 avv = reinterpret_cast<const float4*>(avs)[l16];
  float lsum = 0.f;
  for (int s = grp; s < nzt8; s += 8) {
    int ps = (s < nz0) ? s : 512 + s - nz0;
    int j = eidx[ps];
    float4 x2v = *reinterpret_cast<const float4*>(
        x2b + (size_t)j * 128 + l16 * 4);  // 8 groups x 256B coalesced
    float z, sc = 0.f;
    z = x1v.x + x2v.x; sc = fmaf(z >= 0.f ? z : SLOPE * z, avv.x, sc);
    z = x1v.y + x2v.y; sc = fmaf(z >= 0.f ? z : SLOPE * z, avv.y, sc);
    z = x1v.z + x2v.z; sc = fmaf(z >= 0.f ? z : SLOPE * z, avv.z, sc);
    z = x1v.w + x2v.w; sc = fmaf(z >= 0.f ? z : SLOPE * z, avv.w, sc);
    sc += __shfl_xor(sc, 8, 16);
    sc += __shfl_xor(sc, 4, 16);
    sc += __shfl_xor(sc, 2, 16);
    sc += __shfl_xor(sc, 1, 16);
    if (l16 == 0 && s < nzt) {
      float e = fast_edge_exp(sc);
      evals[ps] = e;
      lsum += e;
    }
  }

  // ---- Phase C: block-reduce row sum (leaders hold partials) ----
#pragma unroll
  for (int off = 32; off > 0; off >>= 1) lsum += __shfl_xor(lsum, off, 64);
  if (lane == 0) wsum[w] = lsum;
  __syncthreads();
  float inv = 1.f / (wsum[0] + wsum[1]);

  // ---- Phase D: thread owns k=tid; 8 coalesced 512B row-gathers/batch ----
  const float* xk = x + (size_t)b * NN * DIN + tid;
  float acc0 = 0.f, acc1 = 0.f;
  for (int s = 0; s < nzt8; s += 8) {
    int j[8];
    float wt[8];
#pragma unroll
    for (int r = 0; r < 8; ++r) {
      int ss = s + r;
      int ps = (ss < nz0) ? ss : 512 + ss - nz0;
      j[r] = eidx[ps];   // LDS broadcast (same across block)
      wt[r] = evals[ps];
    }
    float xv[8];
#pragma unroll
    for (int r = 0; r < 8; ++r) xv[r] = xk[(size_t)j[r] * 128];
#pragma unroll
    for (int r = 0; r < 8; r += 2) {
      acc0 = fmaf(wt[r], xv[r], acc0);
      acc1 = fmaf(wt[r + 1], xv[r + 1], acc1);
    }
  }
  agg[tid] = (acc0 + acc1) * inv;
  __syncthreads();

  // ---- Phase E: thread = (d, k-half); coalesced L1-hot lwT reads ----
  int d = tid & 63;
  int h = tid >> 6;
  const float* lwc = lwT + (size_t)h * 64 * DOUT + d;
  const float* agh = agg + h * 64;
  float o = 0.f;
#pragma unroll 8
  for (int k = 0; k < 64; ++k)
    o = fmaf(agh[k], lwc[k * DOUT], o);
  ep[h][d] = o;
  __syncthreads();
  if (tid < DOUT) {
    float oo = ep[0][tid] + ep[1][tid];
    oo = oo >= 0.f ? oo : SLOPE * oo;
    out[(size_t)bi * DOUT + tid] = oo;
  }
}

extern "C" void kernel_launch(void* const* d_in, const int* in_sizes, int n_in,
                              void* d_out, int out_size, void* d_ws, size_t ws_size,
                              hipStream_t stream) {
  const float* x = (const float*)d_in[0];
  const float* A_shape = (const float*)d_in[1];
  const float* w1 = (const float*)d_in[2];
  const float* w2 = (const float*)d_in[3];
  const float* a = (const float*)d_in[4];
  const float* lin_w = (const float*)d_in[5];
  float* out = (float*)d_out;
  float* x12 = (float*)d_ws;                          // 2 MB
  float* lwT = (float*)d_ws + (size_t)BB * NN * 128;  // 32 KB

  proj_kernel<<<BB * NN + 8, 64, 0, stream>>>(x, w1, w2, lin_w, x12, lwT);
  gat_row_kernel<<<BB * NN, 128, 0, stream>>>(x, A_shape, a, lwT, x12, out);
}